// Round 9
// baseline (168.283 us; speedup 1.0000x reference)
//
#include <hip/hip_runtime.h>

// SAGPool on MI355X, round 9: round-1 register tiling (4x8/thread, 256 thr,
// fewest LDS instrs/CU: ~6.9K b128/layer) + round-8 conflict elimination via
// column-skewed W/T layout (2-way max = free). One LDS buffer B0 serves
// F0 -> T -> H in-place (reg-accumulate, sync, overwrite). H1-3 to global ws.
// Evidence: R1/R7/R8 triple shows time ~ ds_read instrs/CU x conflict factor.

#define NGRAPH 128
#define EPG    1024
#define ETOT   131072
#define DIM    128
#define KSEL   32
#define SA     68       // A row stride
#define SWT    140      // skewed W/T/B0 row stride

// Column skew: c -> c + 4*(c>>5). Octets never straddle a 32-block, so b128
// reads stay aligned; 16 col-octet addrs land 2-per-bank-quad (free).
__device__ __forceinline__ int woff(int k, int c) {
  return k * SWT + c + ((c >> 5) << 2);
}

// LDS layout (floats)
#define O_A    0                     // 64*68  = 4352
#define O_B0   4352                  // 64*140 = 8960 (F0/T/H in-place)
#define O_W    13312                 // 16*140 = 2240 (W chunk)
#define O_PRE  15552                 // 64
#define O_SC   15616                 // 64
#define O_SEL  15680                 // 64
#define LDS_FLOATS 15744
#define LDS_BYTES  (LDS_FLOATS * 4)  // 62976
// tail scratch aliases dead sW region (after layer 3):
#define O_RO   O_W                   // 768
#define O_MH   (O_W + 768)           // 256
#define O_HM   (O_W + 1024)          // 128
#define O_H2M  (O_W + 1152)          // 64

#define FMA8(A, xs, w0, w1) do { \
  A[0] += (xs)*(w0).x; A[1] += (xs)*(w0).y; A[2] += (xs)*(w0).z; A[3] += (xs)*(w0).w; \
  A[4] += (xs)*(w1).x; A[5] += (xs)*(w1).y; A[6] += (xs)*(w1).z; A[7] += (xs)*(w1).w; } while(0)

// One GCN layer: T = B0 @ W (B0 holds features); H = relu(A@T + b) -> B0
// in-place + global Hg; pre[row] += H[row,:].waCol.
__device__ void gcn_layer(float* lds, const float* __restrict__ Wg,
                          const float* __restrict__ bg,
                          const float* __restrict__ waCol,
                          float* __restrict__ Hg, int tid)
{
  float* sA  = lds + O_A;
  float* B0  = lds + O_B0;
  float* sW  = lds + O_W;
  float* pre = lds + O_PRE;
  const int rq = tid >> 4;        // 0..15 -> 4 rows
  const int cb = tid & 15;        // 0..15 -> col octet
  const int r0 = rq * 4;
  const int c0 = cb * 8;

  // ---- phase 1: T = B0 @ W (64x128 @ 128x128), acc in registers ----
  float acc[4][8];
  #pragma unroll
  for (int rr = 0; rr < 4; ++rr)
    #pragma unroll
    for (int cc = 0; cc < 8; ++cc) acc[rr][cc] = 0.f;

  for (int kc = 0; kc < 8; ++kc) {
    { // stage 16 rows of W, skewed
      const float4* src = (const float4*)(Wg + kc * 16 * DIM);
      int i0 = tid, i1 = tid + 256;
      *(float4*)&sW[woff(i0 >> 5, (i0 & 31) * 4)] = src[i0];
      *(float4*)&sW[woff(i1 >> 5, (i1 & 31) * 4)] = src[i1];
    }
    __syncthreads();
    #pragma unroll
    for (int kt = 0; kt < 4; ++kt) {
      const int kl = kt * 4;
      const int kg = kc * 16 + kl;
      float4 xv[4];
      #pragma unroll
      for (int rr = 0; rr < 4; ++rr)
        xv[rr] = *(const float4*)&B0[woff(r0 + rr, kg)];
      float4 w0[4], w1[4];
      #pragma unroll
      for (int i = 0; i < 4; ++i) {
        int base = woff(kl + i, c0);
        w0[i] = *(const float4*)&sW[base];
        w1[i] = *(const float4*)&sW[base + 4];
      }
      #pragma unroll
      for (int rr = 0; rr < 4; ++rr) {
        FMA8(acc[rr], xv[rr].x, w0[0], w1[0]);
        FMA8(acc[rr], xv[rr].y, w0[1], w1[1]);
        FMA8(acc[rr], xv[rr].z, w0[2], w1[2]);
        FMA8(acc[rr], xv[rr].w, w0[3], w1[3]);
      }
    }
    __syncthreads();
  }
  // write T over B0 (all B0 reads done: loop ended with a sync)
  #pragma unroll
  for (int rr = 0; rr < 4; ++rr) {
    int base = woff(r0 + rr, c0);
    *(float4*)&B0[base]     = make_float4(acc[rr][0], acc[rr][1], acc[rr][2], acc[rr][3]);
    *(float4*)&B0[base + 4] = make_float4(acc[rr][4], acc[rr][5], acc[rr][6], acc[rr][7]);
  }
  __syncthreads();

  // ---- phase 2: H = relu(A @ T + b); T == B0 ----
  float4 bv0 = *(const float4*)&bg[c0];
  float4 bv1 = *(const float4*)&bg[c0 + 4];
  float a2[4][8];
  #pragma unroll
  for (int rr = 0; rr < 4; ++rr) {
    a2[rr][0] = bv0.x; a2[rr][1] = bv0.y; a2[rr][2] = bv0.z; a2[rr][3] = bv0.w;
    a2[rr][4] = bv1.x; a2[rr][5] = bv1.y; a2[rr][6] = bv1.z; a2[rr][7] = bv1.w;
  }
  for (int j = 0; j < 64; j += 4) {
    float4 av[4];
    #pragma unroll
    for (int rr = 0; rr < 4; ++rr)
      av[rr] = *(const float4*)&sA[(r0 + rr) * SA + j];
    float4 t0[4], t1[4];
    #pragma unroll
    for (int jj = 0; jj < 4; ++jj) {
      int base = woff(j + jj, c0);
      t0[jj] = *(const float4*)&B0[base];
      t1[jj] = *(const float4*)&B0[base + 4];
    }
    #pragma unroll
    for (int rr = 0; rr < 4; ++rr) {
      FMA8(a2[rr], av[rr].x, t0[0], t1[0]);
      FMA8(a2[rr], av[rr].y, t0[1], t1[1]);
      FMA8(a2[rr], av[rr].z, t0[2], t1[2]);
      FMA8(a2[rr], av[rr].w, t0[3], t1[3]);
    }
  }
  float4 wa0 = *(const float4*)&waCol[c0];
  float4 wa1 = *(const float4*)&waCol[c0 + 4];
  float4 o0[4], o1[4];
  float pp[4];
  #pragma unroll
  for (int rr = 0; rr < 4; ++rr) {
    o0[rr].x = fmaxf(a2[rr][0], 0.f); o0[rr].y = fmaxf(a2[rr][1], 0.f);
    o0[rr].z = fmaxf(a2[rr][2], 0.f); o0[rr].w = fmaxf(a2[rr][3], 0.f);
    o1[rr].x = fmaxf(a2[rr][4], 0.f); o1[rr].y = fmaxf(a2[rr][5], 0.f);
    o1[rr].z = fmaxf(a2[rr][6], 0.f); o1[rr].w = fmaxf(a2[rr][7], 0.f);
    pp[rr] = o0[rr].x*wa0.x + o0[rr].y*wa0.y + o0[rr].z*wa0.z + o0[rr].w*wa0.w
           + o1[rr].x*wa1.x + o1[rr].y*wa1.y + o1[rr].z*wa1.z + o1[rr].w*wa1.w;
  }
  __syncthreads();                 // all T reads done before H overwrite
  #pragma unroll
  for (int rr = 0; rr < 4; ++rr) {
    int base = woff(r0 + rr, c0);
    *(float4*)&B0[base]     = o0[rr];     // B0 becomes this layer's H
    *(float4*)&B0[base + 4] = o1[rr];
    *(float4*)&Hg[(r0 + rr) * DIM + c0]     = o0[rr];
    *(float4*)&Hg[(r0 + rr) * DIM + c0 + 4] = o1[rr];
  }
  #pragma unroll
  for (int rr = 0; rr < 4; ++rr) {
    pp[rr] += __shfl_xor(pp[rr], 1);
    pp[rr] += __shfl_xor(pp[rr], 2);
    pp[rr] += __shfl_xor(pp[rr], 4);
    pp[rr] += __shfl_xor(pp[rr], 8);
  }
  if (cb == 0) {
    #pragma unroll
    for (int rr = 0; rr < 4; ++rr) pre[r0 + rr] += pp[rr];
  }
  __syncthreads();
}

extern "C" __global__ void
sagpool(const float* __restrict__ x,  const int* __restrict__ ei,
        const float* __restrict__ W1, const float* __restrict__ b1,
        const float* __restrict__ W2, const float* __restrict__ b2,
        const float* __restrict__ W3, const float* __restrict__ b3,
        const float* __restrict__ Wa, const float* __restrict__ ba,
        const float* __restrict__ M1, const float* __restrict__ c1,
        const float* __restrict__ M2, const float* __restrict__ c2,
        const float* __restrict__ M3, const float* __restrict__ c3,
        float* __restrict__ h1w, float* __restrict__ h2w,
        float* __restrict__ h3w, float* __restrict__ out)
{
  extern __shared__ float lds[];
  const int g = blockIdx.x, tid = threadIdx.x;
  float* sA  = lds + O_A;
  float* B0  = lds + O_B0;
  float* pre = lds + O_PRE;
  float* sc  = lds + O_SC;   // dinv, later score
  float* sel = lds + O_SEL;
  float* ro  = lds + O_RO;
  float* mh  = lds + O_MH;
  float* hm  = lds + O_HM;
  float* h2m = lds + O_H2M;

  // ---- adjacency: build, +I, D^-1/2 normalize (round-1 code, proven) ----
  for (int i = tid; i < 64 * SA; i += 256) sA[i] = 0.f;
  if (tid < 64) pre[tid] = 0.f;
  __syncthreads();
  {
    const int* srcp = ei + g * EPG;
    const int* dstp = ei + ETOT + g * EPG;
    #pragma unroll
    for (int t = 0; t < 4; ++t) {
      int e = tid + t * 256;
      int s = srcp[e] & 63;
      int d = dstp[e] & 63;
      sA[s * SA + d] = 1.0f;
      sA[d * SA + s] = 1.0f;
    }
  }
  __syncthreads();
  if (tid < 64) sA[tid * SA + tid] += 1.0f;   // +I (self-edge -> 2, matches ref)
  __syncthreads();
  {
    int r = tid >> 2, q = tid & 3;
    float sum = 0.f;
    int jb = q * 16;
    #pragma unroll
    for (int j = 0; j < 16; ++j) sum += sA[r * SA + jb + j];
    sum += __shfl_xor(sum, 1);
    sum += __shfl_xor(sum, 2);
    if (q == 0) sc[r] = 1.0f / sqrtf(sum);
  }
  __syncthreads();
  for (int i = tid; i < 4096; i += 256) {
    int r = i >> 6, c = i & 63;
    sA[r * SA + c] *= sc[r] * sc[c];
  }
  { // stage x into B0 (skewed)
    const float4* xg = (const float4*)(x + g * 64 * DIM);
    for (int i = tid; i < 2048; i += 256)
      *(float4*)&B0[woff(i >> 5, (i & 31) * 4)] = xg[i];
  }
  __syncthreads();

  // ---- 3 GCN layers ----
  gcn_layer(lds, W1, b1, Wa,           h1w + g * 8192, tid);
  gcn_layer(lds, W2, b2, Wa + DIM,     h2w + g * 8192, tid);
  gcn_layer(lds, W3, b3, Wa + 2 * DIM, h3w + g * 8192, tid);

  // ---- score = tanh(A @ pre + ba) ----
  {
    int r = tid >> 2, q = tid & 3;
    float p = 0.f;
    int jb = q * 16;
    #pragma unroll
    for (int j = 0; j < 16; ++j) p += sA[r * SA + jb + j] * pre[jb + j];
    p += __shfl_xor(p, 1);
    p += __shfl_xor(p, 2);
    if (q == 0) sc[r] = tanhf(p + ba[0]);
  }
  __syncthreads();

  // ---- top-K by rank (value desc, index asc = lax.top_k tie order) ----
  if (tid < 64) {
    float mys = sc[tid];
    int cnt = 0;
    for (int j = 0; j < 64; ++j) {
      float sj = sc[j];
      cnt += (sj > mys || (sj == mys && j < tid)) ? 1 : 0;
    }
    sel[tid] = (cnt < KSEL) ? 1.0f : 0.0f;
  }
  __syncthreads();

  // ---- readout: mean || max of score-scaled selected rows (H from global) ----
  for (int c = tid; c < 384; c += 256) {
    int which = c >> 7, cc = c & 127;
    const float* hb = ((which == 0) ? h1w : (which == 1) ? h2w : h3w) + g * 8192;
    float sum = 0.f, mx = -1e30f;
    for (int i = 0; i < 64; ++i) {
      if (sel[i] > 0.5f) {
        float v = sc[i] * hb[i * DIM + cc];
        sum += v;
        mx = fmaxf(mx, v);
      }
    }
    ro[c]       = sum * (1.0f / KSEL);
    ro[384 + c] = mx;
  }
  __syncthreads();

  // ---- MLP: 768 -> 128 -> 64 -> 10 ----
  {
    int j = tid & 127, half = tid >> 7;
    float a = 0.f;
    int k0 = half * 384;
    for (int k = k0; k < k0 + 384; k += 4) {
      float4 r4 = *(const float4*)&ro[k];
      a += r4.x * M1[(k + 0) * DIM + j];
      a += r4.y * M1[(k + 1) * DIM + j];
      a += r4.z * M1[(k + 2) * DIM + j];
      a += r4.w * M1[(k + 3) * DIM + j];
    }
    mh[half * 128 + j] = a;
  }
  __syncthreads();
  if (tid < 128) hm[tid] = fmaxf(mh[tid] + mh[128 + tid] + c1[tid], 0.f);
  __syncthreads();
  if (tid < 64) {
    float a = c2[tid];
    for (int k = 0; k < 128; ++k) a += hm[k] * M2[k * 64 + tid];
    h2m[tid] = fmaxf(a, 0.f);
  }
  __syncthreads();
  if (tid < 10) {
    float a = c3[tid];
    for (int k = 0; k < 64; ++k) a += h2m[k] * M3[k * 10 + tid];
    out[g * 10 + tid] = a;
  }
}

extern "C" void kernel_launch(void* const* d_in, const int* in_sizes, int n_in,
                              void* d_out, int out_size, void* d_ws, size_t ws_size,
                              hipStream_t stream) {
  const float* x  = (const float*)d_in[0];
  const int*   ei = (const int*)d_in[1];
  // d_in[2] (batch) unused: graphs are contiguous 64-node blocks
  const float* W1 = (const float*)d_in[3];
  const float* b1 = (const float*)d_in[4];
  const float* W2 = (const float*)d_in[5];
  const float* b2 = (const float*)d_in[6];
  const float* W3 = (const float*)d_in[7];
  const float* b3 = (const float*)d_in[8];
  const float* Wa = (const float*)d_in[9];
  const float* ba = (const float*)d_in[10];
  const float* M1 = (const float*)d_in[11];
  const float* c1 = (const float*)d_in[12];
  const float* M2 = (const float*)d_in[13];
  const float* c2 = (const float*)d_in[14];
  const float* M3 = (const float*)d_in[15];
  const float* c3 = (const float*)d_in[16];
  float* out = (float*)d_out;

  float* ws  = (float*)d_ws;
  float* h1w = ws;                    // 128*64*128 = 1M floats each
  float* h2w = ws + 1048576;
  float* h3w = ws + 2097152;

  (void)hipFuncSetAttribute(reinterpret_cast<const void*>(sagpool),
                            hipFuncAttributeMaxDynamicSharedMemorySize, LDS_BYTES);
  sagpool<<<NGRAPH, 256, LDS_BYTES, stream>>>(x, ei, W1, b1, W2, b2, W3, b3,
                                              Wa, ba, M1, c1, M2, c2, M3, c3,
                                              h1w, h2w, h3w, out);
}

// Round 10
// 146.762 us; speedup vs baseline: 1.1466x; 1.1466x over previous
//
#include <hip/hip_runtime.h>

// SAGPool on MI355X, round 10: R8 broadcast structure + W via SCALAR loads.
// Evidence: R8's wall is LDS instruction throughput; its W broadcasts
// (4096 b128/CU/layer) are wave-uniform -> move them to the scalar pipe
// (readfirstlane'd col offset => s_load into SGPRs; v_fma takes 1 SGPR
// operand). Deletes W staging + broadcasts + 2 syncs/layer. X/A/T stay in
// LDS (X/A per-row reads, T phase-2 broadcasts). H1-3 to global ws.

#define NGRAPH 128
#define EPG    1024
#define ETOT   131072
#define DIM    128
#define KSEL   32
#define SA     68       // A row stride
#define SF     132      // X/H/T row stride

// LDS layout (floats)
#define O_A    0                     // 64*68  = 4352
#define O_B0   4352                  // 64*132 = 8448 (X -> H in-place)
#define O_T    12800                 // 64*132 = 8448
#define O_PPAR 21248                 // 16*64 = 1024 (per-wave pre partials)
#define O_PRE  22272                 // 64
#define O_SC   22336                 // 64
#define O_SEL  22400                 // 64
#define LDS_FLOATS 22464
#define LDS_BYTES  (LDS_FLOATS * 4)  // 89856
// tail scratch aliases dead sT region (after layer 3):
#define O_RO   O_T                   // 768
#define O_MH   (O_T + 768)           // 1024
#define O_HM   (O_T + 1792)          // 128
#define O_H2M  (O_T + 1920)          // 64

#define FMA8(A, xs, w0, w1) do { \
  A[0] += (xs)*(w0).x; A[1] += (xs)*(w0).y; A[2] += (xs)*(w0).z; A[3] += (xs)*(w0).w; \
  A[4] += (xs)*(w1).x; A[5] += (xs)*(w1).y; A[6] += (xs)*(w1).z; A[7] += (xs)*(w1).w; } while(0)

// One GCN layer. lane r = tid&63 (row), wave w = tid>>6 (col-oct, uniform).
// T = X @ W (W scalar-loaded); H = relu(A@T + b) -> B0 + global Hg;
// pre[r] += H[r,:].waCol via per-wave partials.
__device__ void gcn_layer(float* lds, const float* __restrict__ Wg,
                          const float* __restrict__ bg,
                          const float* __restrict__ waCol,
                          float* __restrict__ Hg, int tid)
{
  float* sA   = lds + O_A;
  float* B0   = lds + O_B0;
  float* sT   = lds + O_T;
  float* ppar = lds + O_PPAR;
  float* pre  = lds + O_PRE;
  const int r  = tid & 63;
  const int w  = tid >> 6;
  const int c0 = __builtin_amdgcn_readfirstlane(w * 8);  // uniform -> s_load path

  // ---- phase 1: T[r][c0..c0+7] = X[r,:] @ W[:,c0..c0+7] ----
  float acc[8] = {0.f,0.f,0.f,0.f,0.f,0.f,0.f,0.f};
  const float* wp = Wg + c0;                  // uniform base
  #pragma unroll 2
  for (int kq = 0; kq < 32; ++kq) {
    float4 xv = *(const float4*)&B0[r * SF + kq * 4];    // per-row LDS read
    const float* wr = wp + (kq * 4) * DIM;               // uniform -> SGPR loads
    float4 w00 = *(const float4*)&wr[0];
    float4 w01 = *(const float4*)&wr[4];
    float4 w10 = *(const float4*)&wr[DIM];
    float4 w11 = *(const float4*)&wr[DIM + 4];
    float4 w20 = *(const float4*)&wr[2 * DIM];
    float4 w21 = *(const float4*)&wr[2 * DIM + 4];
    float4 w30 = *(const float4*)&wr[3 * DIM];
    float4 w31 = *(const float4*)&wr[3 * DIM + 4];
    FMA8(acc, xv.x, w00, w01);
    FMA8(acc, xv.y, w10, w11);
    FMA8(acc, xv.z, w20, w21);
    FMA8(acc, xv.w, w30, w31);
  }
  *(float4*)&sT[r * SF + c0]     = make_float4(acc[0], acc[1], acc[2], acc[3]);
  *(float4*)&sT[r * SF + c0 + 4] = make_float4(acc[4], acc[5], acc[6], acc[7]);
  __syncthreads();

  // ---- phase 2: H[r][c0..] = relu(A[r,:] @ T[:,c0..] + b) ----
  float4 bv0 = *(const float4*)&bg[c0];       // uniform -> scalar
  float4 bv1 = *(const float4*)&bg[c0 + 4];
  float a2[8];
  a2[0] = bv0.x; a2[1] = bv0.y; a2[2] = bv0.z; a2[3] = bv0.w;
  a2[4] = bv1.x; a2[5] = bv1.y; a2[6] = bv1.z; a2[7] = bv1.w;
  #pragma unroll 4
  for (int jq = 0; jq < 16; ++jq) {
    float4 a4 = *(const float4*)&sA[r * SA + jq * 4];    // per-row LDS read
    const float* tb = sT + (jq * 4) * SF + c0;           // wave-uniform -> broadcast
    float4 t0, t1;
    t0 = *(const float4*)&tb[0];      t1 = *(const float4*)&tb[4];
    FMA8(a2, a4.x, t0, t1);
    t0 = *(const float4*)&tb[SF];     t1 = *(const float4*)&tb[SF + 4];
    FMA8(a2, a4.y, t0, t1);
    t0 = *(const float4*)&tb[2 * SF]; t1 = *(const float4*)&tb[2 * SF + 4];
    FMA8(a2, a4.z, t0, t1);
    t0 = *(const float4*)&tb[3 * SF]; t1 = *(const float4*)&tb[3 * SF + 4];
    FMA8(a2, a4.w, t0, t1);
  }
  float4 o0, o1;
  o0.x = fmaxf(a2[0], 0.f); o0.y = fmaxf(a2[1], 0.f);
  o0.z = fmaxf(a2[2], 0.f); o0.w = fmaxf(a2[3], 0.f);
  o1.x = fmaxf(a2[4], 0.f); o1.y = fmaxf(a2[5], 0.f);
  o1.z = fmaxf(a2[6], 0.f); o1.w = fmaxf(a2[7], 0.f);
  // B0 reads (phase 1) were ordered before the phase1->2 sync; safe to
  // overwrite B0 with H now. sT is untouched here.
  *(float4*)&B0[r * SF + c0]      = o0;
  *(float4*)&B0[r * SF + c0 + 4]  = o1;
  *(float4*)&Hg[r * DIM + c0]     = o0;
  *(float4*)&Hg[r * DIM + c0 + 4] = o1;
  float4 wa0 = *(const float4*)&waCol[c0];
  float4 wa1 = *(const float4*)&waCol[c0 + 4];
  ppar[w * 64 + r] = o0.x*wa0.x + o0.y*wa0.y + o0.z*wa0.z + o0.w*wa0.w
                   + o1.x*wa1.x + o1.y*wa1.y + o1.z*wa1.z + o1.w*wa1.w;
  __syncthreads();
  if (tid < 64) {                   // reduce 16 wave-partials -> pre
    float s = 0.f;
    #pragma unroll
    for (int q = 0; q < 16; ++q) s += ppar[q * 64 + tid];
    pre[tid] += s;
  }
  __syncthreads();                  // B0(H) + pre visible to next phase
}

extern "C" __global__ void __launch_bounds__(1024)
sagpool(const float* __restrict__ x,  const int* __restrict__ ei,
        const float* __restrict__ W1, const float* __restrict__ b1,
        const float* __restrict__ W2, const float* __restrict__ b2,
        const float* __restrict__ W3, const float* __restrict__ b3,
        const float* __restrict__ Wa, const float* __restrict__ ba,
        const float* __restrict__ M1, const float* __restrict__ c1,
        const float* __restrict__ M2, const float* __restrict__ c2,
        const float* __restrict__ M3, const float* __restrict__ c3,
        float* __restrict__ h1w, float* __restrict__ h2w,
        float* __restrict__ h3w, float* __restrict__ out)
{
  extern __shared__ float lds[];
  const int g = blockIdx.x, tid = threadIdx.x;
  float* sA  = lds + O_A;
  float* B0  = lds + O_B0;
  float* pre = lds + O_PRE;
  float* sc  = lds + O_SC;   // dinv, later score
  float* sel = lds + O_SEL;
  float* ro  = lds + O_RO;
  float* mh  = lds + O_MH;
  float* hm  = lds + O_HM;
  float* h2m = lds + O_H2M;

  // ---- adjacency: build, +I, D^-1/2 normalize ----
  for (int i = tid; i < 64 * SA; i += 1024) sA[i] = 0.f;
  if (tid < 64) pre[tid] = 0.f;
  __syncthreads();
  {
    int s = ei[g * EPG + tid] & 63;
    int d = ei[ETOT + g * EPG + tid] & 63;
    sA[s * SA + d] = 1.0f;
    sA[d * SA + s] = 1.0f;
  }
  __syncthreads();
  if (tid < 64) sA[tid * SA + tid] += 1.0f;   // +I (self-edge -> 2, matches ref)
  __syncthreads();
  {
    int r = tid >> 4, q = tid & 15;
    float sum = sA[r * SA + q * 4]     + sA[r * SA + q * 4 + 1]
              + sA[r * SA + q * 4 + 2] + sA[r * SA + q * 4 + 3];
    sum += __shfl_xor(sum, 1);
    sum += __shfl_xor(sum, 2);
    sum += __shfl_xor(sum, 4);
    sum += __shfl_xor(sum, 8);
    if (q == 0) sc[r] = 1.0f / sqrtf(sum);
  }
  __syncthreads();
  for (int i = tid; i < 4096; i += 1024) {
    int r = i >> 6, c = i & 63;
    sA[r * SA + c] *= sc[r] * sc[c];
  }
  { // stage x into B0 [64][132]
    const float4* xg = (const float4*)(x + g * 64 * DIM);
    for (int i = tid; i < 2048; i += 1024) {
      int r = i >> 5, q = i & 31;
      *(float4*)&B0[r * SF + q * 4] = xg[i];
    }
  }
  __syncthreads();

  // ---- 3 GCN layers ----
  gcn_layer(lds, W1, b1, Wa,           h1w + g * 8192, tid);
  gcn_layer(lds, W2, b2, Wa + DIM,     h2w + g * 8192, tid);
  gcn_layer(lds, W3, b3, Wa + 2 * DIM, h3w + g * 8192, tid);

  // ---- score = tanh(A @ pre + ba) ----
  {
    int r = tid >> 4, q = tid & 15;
    float p = sA[r * SA + q * 4]     * pre[q * 4]
            + sA[r * SA + q * 4 + 1] * pre[q * 4 + 1]
            + sA[r * SA + q * 4 + 2] * pre[q * 4 + 2]
            + sA[r * SA + q * 4 + 3] * pre[q * 4 + 3];
    p += __shfl_xor(p, 1);
    p += __shfl_xor(p, 2);
    p += __shfl_xor(p, 4);
    p += __shfl_xor(p, 8);
    if (q == 0) sc[r] = tanhf(p + ba[0]);
  }
  __syncthreads();

  // ---- top-K by rank (value desc, index asc = lax.top_k tie order) ----
  if (tid < 64) {
    float mys = sc[tid];
    int cnt = 0;
    for (int j = 0; j < 64; ++j) {
      float sj = sc[j];
      cnt += (sj > mys || (sj == mys && j < tid)) ? 1 : 0;
    }
    sel[tid] = (cnt < KSEL) ? 1.0f : 0.0f;
  }
  __syncthreads();

  // ---- readout: mean || max of score-scaled selected rows ----
  if (tid < 768) {
    int c = tid >> 1, half = tid & 1;          // c in 0..383
    int which = c >> 7, cc = c & 127;
    const float* hb = ((which == 0) ? h1w : (which == 1) ? h2w : h3w) + g * 8192;
    float sum = 0.f, mx = -1e30f;
    for (int i = half * 32; i < half * 32 + 32; ++i) {
      if (sel[i] > 0.5f) {
        float v = sc[i] * hb[i * DIM + cc];
        sum += v;
        mx = fmaxf(mx, v);
      }
    }
    sum += __shfl_xor(sum, 1);
    mx = fmaxf(mx, __shfl_xor(mx, 1));
    if (half == 0) {
      ro[c]       = sum * (1.0f / KSEL);
      ro[384 + c] = mx;
    }
  }
  __syncthreads();

  // ---- MLP: 768 -> 128 -> 64 -> 10 ----
  {
    int j = tid & 127, oc = tid >> 7;          // 8 k-chunks of 96
    float a = 0.f;
    int k0 = oc * 96;
    for (int k = k0; k < k0 + 96; k += 4) {
      float4 r4 = *(const float4*)&ro[k];
      a += r4.x * M1[(k + 0) * DIM + j];
      a += r4.y * M1[(k + 1) * DIM + j];
      a += r4.z * M1[(k + 2) * DIM + j];
      a += r4.w * M1[(k + 3) * DIM + j];
    }
    mh[oc * 128 + j] = a;
  }
  __syncthreads();
  if (tid < 128) {
    float v = c1[tid];
    #pragma unroll
    for (int q = 0; q < 8; ++q) v += mh[q * 128 + tid];
    hm[tid] = fmaxf(v, 0.f);
  }
  __syncthreads();
  if (tid < 64) {
    float a = c2[tid];
    for (int k = 0; k < 128; ++k) a += hm[k] * M2[k * 64 + tid];
    h2m[tid] = fmaxf(a, 0.f);
  }
  __syncthreads();
  if (tid < 10) {
    float a = c3[tid];
    for (int k = 0; k < 64; ++k) a += h2m[k] * M3[k * 10 + tid];
    out[g * 10 + tid] = a;
  }
}

extern "C" void kernel_launch(void* const* d_in, const int* in_sizes, int n_in,
                              void* d_out, int out_size, void* d_ws, size_t ws_size,
                              hipStream_t stream) {
  const float* x  = (const float*)d_in[0];
  const int*   ei = (const int*)d_in[1];
  // d_in[2] (batch) unused: graphs are contiguous 64-node blocks
  const float* W1 = (const float*)d_in[3];
  const float* b1 = (const float*)d_in[4];
  const float* W2 = (const float*)d_in[5];
  const float* b2 = (const float*)d_in[6];
  const float* W3 = (const float*)d_in[7];
  const float* b3 = (const float*)d_in[8];
  const float* Wa = (const float*)d_in[9];
  const float* ba = (const float*)d_in[10];
  const float* M1 = (const float*)d_in[11];
  const float* c1 = (const float*)d_in[12];
  const float* M2 = (const float*)d_in[13];
  const float* c2 = (const float*)d_in[14];
  const float* M3 = (const float*)d_in[15];
  const float* c3 = (const float*)d_in[16];
  float* out = (float*)d_out;

  float* ws  = (float*)d_ws;
  float* h1w = ws;                    // 128*64*128 = 1M floats each
  float* h2w = ws + 1048576;
  float* h3w = ws + 2097152;

  (void)hipFuncSetAttribute(reinterpret_cast<const void*>(sagpool),
                            hipFuncAttributeMaxDynamicSharedMemorySize, LDS_BYTES);
  sagpool<<<NGRAPH, 1024, LDS_BYTES, stream>>>(x, ei, W1, b1, W2, b2, W3, b3,
                                               Wa, ba, M1, c1, M2, c2, M3, c3,
                                               h1w, h2w, h3w, out);
}